// Round 3
// baseline (450.136 us; speedup 1.0000x reference)
//
#include <hip/hip_runtime.h>

// TranslateCube: out[n, y, x] = bilinear sample of img[n] at (y - dy[n], x - dx[n]),
// zero fill outside. B*T = 1024 images, H = W = 256, fp32.
//
// v4: pure-streaming, register-resident (no LDS, no barrier).
//   tx/ty uniform per image ->
//     wx = frac(-tx), wy = frac(-ty)             (SGPR scalars)
//     sx = floor(-tx) = a + off, a = sx & ~3, off in [0,3]
//   Each lane owns output cols [4*lane, 4*lane+3] of a 32-row band.
//   Its source window for any row is floats [g, g+7], g = 4*lane + a  (16B aligned)
//   -> two aligned float4 loads per SOURCE row.  The x-interp
//     t(R) = (1-wx)*src[R][x+sx] + wx*src[R][x+sx+1]
//   is computed ONCE per source row; the y-interp combines t(R), t(R+1), where
//   t(R) is reused from the previous iteration in registers.  Per output row
//   per lane: 32B aligned loads (new source row), ~16 VALU, 16B aligned store.
//   off is uniform -> switch into 4 template instantiations where the window
//   permutation is pure register naming (zero instructions).
//   Boundary zeros: groups are 4-aligned so they are fully inside or fully
//   outside [0,256) -> simple per-lane masks; row validity is a scalar branch.
//
//   No LDS round-trip, no __syncthreads, no block phase structure: every wave
//   continuously issues load/store traffic -> should track the copy ceiling.
//
//   Numerics: identical expression tree to v3 (passed, absmax 0.0156):
//   t = omwx*c00 + wx*c01;  out = omwy*t(R0) + wy*t(R1).
//
// Mapping: grid = (B*T)*2 blocks x 256 threads; block = 4 waves; each wave
// streams one 32-row band. 2048 blocks = 8 blocks/CU = 32 waves/CU exactly.

constexpr int HH  = 256;
constexpr int WW  = 256;
constexpr int RPW = 32;    // output rows per wave

__device__ __forceinline__ void load_row(const float* __restrict__ base, int R,
                                         int g, int g2, bool gok, bool g2ok,
                                         float4& V0, float4& V1)
{
    V0 = make_float4(0.f, 0.f, 0.f, 0.f);
    V1 = make_float4(0.f, 0.f, 0.f, 0.f);
    if ((unsigned)R < (unsigned)HH) {              // uniform -> scalar branch
        const float* __restrict__ rp = base + R * WW;
        if (gok)  V0 = *(const float4*)(rp + g);   // aligned 16B
        if (g2ok) V1 = *(const float4*)(rp + g2);  // adjacent lane's V0 -> L1
    }
}

template<int OFF>
__device__ __forceinline__ float4 xinterp(const float4& V0, const float4& V1,
                                          float wx, float omwx)
{
    // Window W[0..7] = {V0.x..V0.w, V1.x..V1.w}; c00 = W[OFF..OFF+3],
    // c01 = W[OFF+1..OFF+4].  Compile-time OFF -> pure register selection.
    float c00x, c00y, c00z, c00w, c01x, c01y, c01z, c01w;
    if constexpr (OFF == 0) {
        c00x=V0.x; c00y=V0.y; c00z=V0.z; c00w=V0.w;
        c01x=V0.y; c01y=V0.z; c01z=V0.w; c01w=V1.x;
    } else if constexpr (OFF == 1) {
        c00x=V0.y; c00y=V0.z; c00z=V0.w; c00w=V1.x;
        c01x=V0.z; c01y=V0.w; c01z=V1.x; c01w=V1.y;
    } else if constexpr (OFF == 2) {
        c00x=V0.z; c00y=V0.w; c00z=V1.x; c00w=V1.y;
        c01x=V0.w; c01y=V1.x; c01z=V1.y; c01w=V1.z;
    } else {
        c00x=V0.w; c00y=V1.x; c00z=V1.y; c00w=V1.z;
        c01x=V1.x; c01y=V1.y; c01z=V1.z; c01w=V1.w;
    }
    float4 t;
    t.x = omwx * c00x + wx * c01x;
    t.y = omwx * c00y + wx * c01y;
    t.z = omwx * c00z + wx * c01z;
    t.w = omwx * c00w + wx * c01w;
    return t;
}

template<int OFF>
__device__ __forceinline__ void wave_band(const float* __restrict__ base,
                                          float* __restrict__ outb,
                                          int yb, int sy,
                                          int g, int g2, bool gok, bool g2ok,
                                          float wx, float omwx,
                                          float wy, float omwy, int lane)
{
    const int R = yb + sy;                  // first source row of the band
    float4 A0, A1, B0, B1;
    load_row(base, R,     g, g2, gok, g2ok, A0, A1);
    load_row(base, R + 1, g, g2, gok, g2ok, B0, B1);
    float4 tprev = xinterp<OFF>(A0, A1, wx, omwx);

    float* op = outb + (size_t)yb * WW + (lane << 2);

    #pragma unroll 2
    for (int r = 0; r < RPW - 1; ++r) {
        float4 C0, C1;                       // prefetch source row r+2
        load_row(base, R + 2 + r, g, g2, gok, g2ok, C0, C1);
        const float4 tcur = xinterp<OFF>(B0, B1, wx, omwx);
        float4 o;
        o.x = omwy * tprev.x + wy * tcur.x;
        o.y = omwy * tprev.y + wy * tcur.y;
        o.z = omwy * tprev.z + wy * tcur.z;
        o.w = omwy * tprev.w + wy * tcur.w;
        *(float4*)op = o;                    // coalesced aligned 16B store
        op += WW;
        tprev = tcur;  B0 = C0;  B1 = C1;
    }
    {   // last row of the band (no further prefetch)
        const float4 tcur = xinterp<OFF>(B0, B1, wx, omwx);
        float4 o;
        o.x = omwy * tprev.x + wy * tcur.x;
        o.y = omwy * tprev.y + wy * tcur.y;
        o.z = omwy * tprev.z + wy * tcur.z;
        o.w = omwy * tprev.w + wy * tcur.w;
        *(float4*)op = o;
    }
}

__global__ __launch_bounds__(256) void translate_kernel(
    const float* __restrict__ img,
    const float* __restrict__ dx,
    const float* __restrict__ dy,
    float* __restrict__ out)
{
    const int n    = blockIdx.x >> 1;          // image index
    const int half = blockIdx.x & 1;           // top/bottom 128 rows
    const int tid  = threadIdx.x;
    const int lane = tid & 63;
    const int wv   = tid >> 6;
    const int yb   = half * 128 + wv * RPW;    // this wave's first output row

    const float tx = dx[n];                    // wave-uniform -> scalar
    const float ty = dy[n];

    const float fxf = floorf(-tx);
    const float fyf = floorf(-ty);
    const float wx   = (-tx) - fxf;            // in [0,1)
    const float wy   = (-ty) - fyf;
    const float omwx = 1.0f - wx;
    const float omwy = 1.0f - wy;
    const int sx = (int)fxf;
    const int sy = (int)fyf;
    const int a   = sx & ~3;                   // 4-aligned window base shift
    const int off = sx - a;                    // 0..3, uniform per image

    const int g  = (lane << 2) + a;            // lane's first source col
    const int g2 = g + 4;
    // groups are 4-aligned -> fully inside image iff (unsigned)g < 256
    const bool gok  = (unsigned)g  < (unsigned)WW;
    const bool g2ok = (unsigned)g2 < (unsigned)WW;

    const float* __restrict__ base = img + (size_t)n * (HH * WW);
    float* __restrict__ outb       = out + (size_t)n * (HH * WW);

    switch (off) {
        case 0: wave_band<0>(base, outb, yb, sy, g, g2, gok, g2ok, wx, omwx, wy, omwy, lane); break;
        case 1: wave_band<1>(base, outb, yb, sy, g, g2, gok, g2ok, wx, omwx, wy, omwy, lane); break;
        case 2: wave_band<2>(base, outb, yb, sy, g, g2, gok, g2ok, wx, omwx, wy, omwy, lane); break;
        default: wave_band<3>(base, outb, yb, sy, g, g2, gok, g2ok, wx, omwx, wy, omwy, lane); break;
    }
}

extern "C" void kernel_launch(void* const* d_in, const int* in_sizes, int n_in,
                              void* d_out, int out_size, void* d_ws, size_t ws_size,
                              hipStream_t stream) {
    const float* img = (const float*)d_in[0];  // [B,T,H,W] fp32
    const float* dx  = (const float*)d_in[1];  // [B,T]
    const float* dy  = (const float*)d_in[2];  // [B,T]
    // d_in[3] = winsize (unused)
    float* out = (float*)d_out;

    const int BT = in_sizes[1];                // number of images (B*T)
    const int nblocks = BT * 2;                // 2 blocks (4 waves each) per image

    translate_kernel<<<nblocks, 256, 0, stream>>>(img, dx, dy, out);
}